// Round 2
// baseline (350.180 us; speedup 1.0000x reference)
//
#include <hip/hip_runtime.h>
#include <math.h>

// Problem constants (from reference): x [B, C, L] f32, out [B, C*10] f32
constexpr int B = 64;
constexpr int C = 8;
constexpr int L = 131072;
constexpr int ROWS = B * C;          // 512
constexpr int BLOCK = 1024;          // 16 waves
constexpr int NWAVES = BLOCK / 64;   // 16
constexpr int PER_THREAD = L / BLOCK;    // 128 elements
constexpr int VEC_ITERS = PER_THREAD / 4; // 32 float4 loads per thread

__global__ __launch_bounds__(BLOCK, 2)
void stat_kernel(const float* __restrict__ x, float* __restrict__ out) {
    const int row = blockIdx.x;                // one block per (b,c) row
    const int tid = threadIdx.x;

    const float4* __restrict__ xr =
        reinterpret_cast<const float4*>(x + (size_t)row * L);

    double s1 = 0.0, s2 = 0.0, s3 = 0.0, s4 = 0.0, sa = 0.0;
    float mx = -INFINITY, mn = INFINITY;

    // Coalesced streaming: thread t reads float4 at t + k*BLOCK.
    #pragma unroll 4
    for (int k = 0; k < VEC_ITERS; ++k) {
        float4 v = xr[tid + k * BLOCK];
        {
            double d = (double)v.x; double d2 = d * d;
            s1 += d; s2 = fma(d, d, s2); s3 = fma(d2, d, s3); s4 = fma(d2, d2, s4);
            sa += fabs(d); mx = fmaxf(mx, v.x); mn = fminf(mn, v.x);
        }
        {
            double d = (double)v.y; double d2 = d * d;
            s1 += d; s2 = fma(d, d, s2); s3 = fma(d2, d, s3); s4 = fma(d2, d2, s4);
            sa += fabs(d); mx = fmaxf(mx, v.y); mn = fminf(mn, v.y);
        }
        {
            double d = (double)v.z; double d2 = d * d;
            s1 += d; s2 = fma(d, d, s2); s3 = fma(d2, d, s3); s4 = fma(d2, d2, s4);
            sa += fabs(d); mx = fmaxf(mx, v.z); mn = fminf(mn, v.z);
        }
        {
            double d = (double)v.w; double d2 = d * d;
            s1 += d; s2 = fma(d, d, s2); s3 = fma(d2, d, s3); s4 = fma(d2, d2, s4);
            sa += fabs(d); mx = fmaxf(mx, v.w); mn = fminf(mn, v.w);
        }
    }

    // ---- wave (64-lane) butterfly reduction ----
    #pragma unroll
    for (int off = 32; off >= 1; off >>= 1) {
        s1 += __shfl_xor(s1, off);
        s2 += __shfl_xor(s2, off);
        s3 += __shfl_xor(s3, off);
        s4 += __shfl_xor(s4, off);
        sa += __shfl_xor(sa, off);
        mx = fmaxf(mx, __shfl_xor(mx, off));
        mn = fminf(mn, __shfl_xor(mn, off));
    }

    // ---- cross-wave reduction via LDS ----
    __shared__ double ls1[NWAVES], ls2[NWAVES], ls3[NWAVES], ls4[NWAVES], lsa[NWAVES];
    __shared__ float lmx[NWAVES], lmn[NWAVES];

    const int wave = tid >> 6;
    const int lane = tid & 63;
    if (lane == 0) {
        ls1[wave] = s1; ls2[wave] = s2; ls3[wave] = s3; ls4[wave] = s4; lsa[wave] = sa;
        lmx[wave] = mx; lmn[wave] = mn;
    }
    __syncthreads();

    if (tid == 0) {
        double t1 = 0, t2 = 0, t3 = 0, t4 = 0, ta = 0;
        float tmx = -INFINITY, tmn = INFINITY;
        #pragma unroll
        for (int w = 0; w < NWAVES; ++w) {
            t1 += ls1[w]; t2 += ls2[w]; t3 += ls3[w]; t4 += ls4[w]; ta += lsa[w];
            tmx = fmaxf(tmx, lmx[w]); tmn = fminf(tmn, lmn[w]);
        }

        const double Ld = (double)L;
        const double mean = t1 / Ld;
        const double rms  = sqrt(t2 / Ld);
        const double var  = (t2 - t1 * t1 / Ld) / (Ld - 1.0);
        const double sd   = sqrt(var);
        const double mu   = mean;
        // central moments from raw moments
        const double m3 = t3 - 3.0 * mu * t2 + 2.0 * Ld * mu * mu * mu;
        const double m4 = t4 - 4.0 * mu * t3 + 6.0 * mu * mu * t2
                          - 3.0 * Ld * mu * mu * mu * mu;
        const double skew  = m3 / (sd * sd * sd) * Ld / ((Ld - 1.0) * (Ld - 2.0));
        const double kurto = Ld / ((Ld - 1.0) * (Ld - 1.0)) * m4 / (var * var) - 3.0;
        const double meanabs = ta / Ld;
        const double absmax  = fmax(fabs((double)tmx), fabs((double)tmn));
        const double crest   = absmax / rms;
        const double impulse = ((double)tmx - (double)tmn) / meanabs;
        const double shapef  = rms / meanabs;

        const int b = row / C;
        const int c = row % C;
        float* o = out + (size_t)b * (C * 10) + c;
        o[0 * C] = (float)mean;
        o[1 * C] = (float)tmx;
        o[2 * C] = (float)tmn;
        o[3 * C] = (float)rms;
        o[4 * C] = (float)var;
        o[5 * C] = (float)skew;
        o[6 * C] = (float)kurto;
        o[7 * C] = (float)crest;
        o[8 * C] = (float)impulse;
        o[9 * C] = (float)shapef;
    }
}

extern "C" void kernel_launch(void* const* d_in, const int* in_sizes, int n_in,
                              void* d_out, int out_size, void* d_ws, size_t ws_size,
                              hipStream_t stream) {
    const float* x = (const float*)d_in[0];
    float* out = (float*)d_out;
    stat_kernel<<<ROWS, BLOCK, 0, stream>>>(x, out);
}